// Round 5
// baseline (241.081 us; speedup 1.0000x reference)
//
#include <hip/hip_runtime.h>
#include <cstdint>
#include <cstddef>

typedef __attribute__((ext_vector_type(8))) short bf16x8;
typedef __attribute__((ext_vector_type(4))) short bf16x4;
typedef __attribute__((ext_vector_type(4))) float f32x4;

constexpr int Bsz = 4, Ssz = 2048, Dsz = 1024, Hn = 16, HDsz = 64;
constexpr int Msz = Bsz * Ssz; // 8192 rows of x
constexpr float LOG2E = 1.4426950408889634f;

// K=32 bf16 MFMA. NOTE: do NOT gate amdgcn builtins with __has_builtin —
// it returns false in the HIP host pass.
#define MFMA32(a, b, c) __builtin_amdgcn_mfma_f32_16x16x32_bf16(a, b, c, 0, 0, 0)

__device__ __forceinline__ unsigned short f2bf(float f) {
  union { float f; unsigned int u; } v; v.f = f;
  unsigned int r = v.u + 0x7fffu + ((v.u >> 16) & 1u);
  return (unsigned short)(r >> 16);
}

// async 16B global -> LDS (wave-uniform LDS base + lane*16)
typedef __attribute__((address_space(1))) const unsigned int gu32;
typedef __attribute__((address_space(3))) unsigned int lu32;
__device__ __forceinline__ void async_cp16(const unsigned short* g, unsigned short* l) {
  __builtin_amdgcn_global_load_lds((gu32*)g, (lu32*)l, 16, 0, 0);
}

// ---------- fused: 4x W-transpose (z=0..3) + x fp32->bf16 (z=4) ----------
__global__ void prep_kernel(const float* __restrict__ x, unsigned short* __restrict__ xb,
                            const float* __restrict__ W0, const float* __restrict__ W1,
                            const float* __restrict__ W2, const float* __restrict__ W3,
                            unsigned short* __restrict__ T0, unsigned short* __restrict__ T1,
                            unsigned short* __restrict__ T2, unsigned short* __restrict__ T3) {
  const int z = blockIdx.z;
  if (z == 4) {  // x convert: 1024 blocks x 256 thr x 8 float4
    const int i0 = (blockIdx.y * 32 + blockIdx.x) * 2048 + threadIdx.x;
#pragma unroll
    for (int j = 0; j < 8; j++) {
      const int i = i0 + j * 256;
      const float4 v = reinterpret_cast<const float4*>(x)[i];
      ushort4 o;
      o.x = f2bf(v.x); o.y = f2bf(v.y); o.z = f2bf(v.z); o.w = f2bf(v.w);
      reinterpret_cast<ushort4*>(xb)[i] = o;
    }
    return;
  }
  __shared__ float tile[32][33];
  const float* W = (z == 0) ? W0 : (z == 1) ? W1 : (z == 2) ? W2 : W3;
  unsigned short* Wt = (z == 0) ? T0 : (z == 1) ? T1 : (z == 2) ? T2 : T3;
  int tx = threadIdx.x & 31, ty = threadIdx.x >> 5; // 32 x 8
  int bx = blockIdx.x, by = blockIdx.y;
#pragma unroll
  for (int i = 0; i < 4; i++) {
    int k = by * 32 + ty + i * 8;
    tile[ty + i * 8][tx] = W[k * Dsz + bx * 32 + tx];
  }
  __syncthreads();
#pragma unroll
  for (int i = 0; i < 4; i++) {
    int nrow = bx * 32 + ty + i * 8;
    Wt[nrow * Dsz + by * 32 + tx] = f2bf(tile[tx][ty + i * 8]);
  }
}

// ---------- 128x128-tile, BK=64, 512 threads (8 waves, 32x64 acc/wave) ----------
// XOR-swizzled async-staged bf16 GEMM, C = A[M,K] * Bt[N,K]^T.
// bm-chunked bijective XCD swizzle (mechanism verified round 2: FETCH 103->41MB;
// round 4 on this kernel: FETCH 76.8->49.2MB): both dispatch grids have
// total % 8 == 0. XCD x owns bm in [8x, 8x+8) x all bn -> per-XCD A working
// set = 2MB (L2-resident), B panel shared via L3.
enum { EPI_QKV = 0, EPI_OUT = 1 };

template <int EPI>
__global__ __launch_bounds__(512, 4)
void gemm_bk64(const unsigned short* __restrict__ A,
               const unsigned short* __restrict__ Bt,
               unsigned short* __restrict__ Qh,
               unsigned short* __restrict__ Kh,
               unsigned short* __restrict__ Vth,
               float* __restrict__ Out,
               const float* __restrict__ bias) {
  __shared__ unsigned short As[128 * 64];
  __shared__ unsigned short Bs[128 * 64];

  const int tid = threadIdx.x;
  const int w = tid >> 6, lane = tid & 63;
  const int l15 = lane & 15, quad = lane >> 4;
  const int wr = w >> 1, wc = w & 1;
  // bijective XCD swizzle: orig -> (xcd, idx) -> (bm = xcd*8 + idx%8, bn = idx/8)
  const int orig = blockIdx.y * gridDim.x + blockIdx.x;
  const int xcd = orig & 7, idx = orig >> 3;
  const int bm = (xcd << 3) | (idx & 7);
  const int bn = idx >> 3;
  const int rr = lane >> 3;                 // row within 8-row group
  const int scoff = ((lane & 7) ^ rr) * 8;  // swizzled source col (shorts)

  f32x4 acc[2][4];
#pragma unroll
  for (int i = 0; i < 2; i++)
#pragma unroll
    for (int j = 0; j < 4; j++) acc[i][j] = (f32x4){0.f, 0.f, 0.f, 0.f};

  const int rowA0 = bm * 128, rowB0 = bn * 128;

  for (int kt = 0; kt < Dsz / 64; kt++) {
#pragma unroll
    for (int i = 0; i < 2; i++) {
      const int r8 = w * 16 + i * 8;
      async_cp16(&A[(size_t)(rowA0 + r8 + rr) * Dsz + kt * 64 + scoff], &As[r8 * 64]);
      async_cp16(&Bt[(size_t)(rowB0 + r8 + rr) * Dsz + kt * 64 + scoff], &Bs[r8 * 64]);
    }
    __syncthreads();

#pragma unroll
    for (int ks = 0; ks < 2; ks++) {
      bf16x8 af[2], bfr[4];
#pragma unroll
      for (int t = 0; t < 2; t++) {
        const int ra = wr * 32 + t * 16 + l15;
        af[t] = *reinterpret_cast<const bf16x8*>(
            &As[ra * 64 + (((ks * 4 + quad) ^ (ra & 7)) * 8)]);
      }
#pragma unroll
      for (int t = 0; t < 4; t++) {
        const int rb = wc * 64 + t * 16 + l15;
        bfr[t] = *reinterpret_cast<const bf16x8*>(
            &Bs[rb * 64 + (((ks * 4 + quad) ^ (rb & 7)) * 8)]);
      }
#pragma unroll
      for (int i = 0; i < 2; i++)
#pragma unroll
        for (int j = 0; j < 4; j++)
          acc[i][j] = MFMA32(af[i], bfr[j], acc[i][j]);
    }
    __syncthreads();
  }

  if (EPI == EPI_QKV) {
    const int proj = (bn * 128) >> 10;  // block-uniform: 0=Q 1=K 2=V
#pragma unroll
    for (int i = 0; i < 2; i++) {
#pragma unroll
      for (int j = 0; j < 4; j++) {
        const int n = bn * 128 + wc * 64 + j * 16 + l15;
        const int nn = n & 1023, h = nn >> 6, hd = nn & 63;
        const int m0 = bm * 128 + wr * 32 + i * 16 + quad * 4;
        const int b = m0 >> 11, s0 = m0 & (Ssz - 1);
        if (proj == 0) {
#pragma unroll
          for (int r = 0; r < 4; r++)
            Qh[((size_t)(b * Hn + h) * Ssz + s0 + r) * HDsz + hd] =
                f2bf(acc[i][j][r] * (0.125f * LOG2E));
        } else if (proj == 1) {
#pragma unroll
          for (int r = 0; r < 4; r++)
            Kh[((size_t)(b * Hn + h) * Ssz + s0 + r) * HDsz + hd] = f2bf(acc[i][j][r]);
        } else {
          ushort4 o;
          o.x = f2bf(acc[i][j][0]); o.y = f2bf(acc[i][j][1]);
          o.z = f2bf(acc[i][j][2]); o.w = f2bf(acc[i][j][3]);
          *reinterpret_cast<ushort4*>(
              &Vth[((size_t)(b * Hn + h) * HDsz + hd) * Ssz + s0]) = o;
        }
      }
    }
  } else {
#pragma unroll
    for (int i = 0; i < 2; i++) {
#pragma unroll
      for (int j = 0; j < 4; j++) {
        const int n = bn * 128 + wc * 64 + j * 16 + l15;
        const int m0 = bm * 128 + wr * 32 + i * 16 + quad * 4;
#pragma unroll
        for (int r = 0; r < 4; r++)
          Out[(size_t)(m0 + r) * Dsz + n] = acc[i][j][r] + bias[n];
      }
    }
  }
}

// ---------- flash attention: 128-row tiles, balanced t-perm, S^T + reg P ----------
// grid (16,64) = 1024 blocks (all co-resident, 4/CU). t = perm(g) with
// g=linear>>6: per-CU t-sets {15-a, 8+a, 7-a, a} -> exactly 68 kv-iters per CU,
// and all 4 blocks of a CU share one bh (K/V L2 reuse). XCD: blocks of a bh
// share linear%8. 4-bit storage swizzle h = (row&7)^(((row>>3)&1)<<2) kills
// the l15+-8 b64 bank aliasing.
// NOTE (round-3 lesson): single-buffer stage->sync->compute->sync is the
// right structure here — 4 blocks/CU TLP already hides stage latency (m114);
// intra-block prefetch added 6.5e6 LDS bank-conflict cycles and +10%.
// ROUND-5 CHANGE: PV on K=32 MFMA. Counter accounting (r3: MfmaUtil 30.6% vs
// 6.4% full-rate expectation) fits v_mfma_f32_16x16x16bf16_1k at ~1/4 rate
// (~19 cyc) on gfx950. PV's A-frag (P: row=q@l15, k=kv@quad*8+j) is built
// from the S^T C-layout (kv@quad*4+r) via cross-quad ds_bpermute:
//   frag u32 slot m (k=quad*8+2m,+2m+1): chunk tn = 2C + (quad>>1),
//   src quad = 2(quad&1) + (m>>1), src reg = pk[tn][tm][m&1]
//   -> src lane = l15 + 32*(quad&1) (+16 for m>=2); chunk picked by quad>>1.
__global__ __launch_bounds__(256, 4)
void flash_kernel(const unsigned short* __restrict__ Q,
                  const unsigned short* __restrict__ Kg,
                  const unsigned short* __restrict__ Vt,
                  unsigned short* __restrict__ AO) {
  __shared__ unsigned short Ks[64 * 64];
  __shared__ unsigned short Vs[64 * 64];

  const int tid = threadIdx.x;
  const int w = tid >> 6, lane = tid & 63;
  const int l15 = lane & 15, quad = lane >> 4;
  const int rr = lane >> 3;

  const int linear = blockIdx.y * 16 + blockIdx.x;
  const int bh = (linear & 7) * 8 + ((linear >> 3) & 7);
  const int g = linear >> 6, gk = g >> 2, ga = g & 3;
  const int t = (gk == 0) ? 15 - ga : (gk == 1) ? 8 + ga : (gk == 2) ? 7 - ga : ga;

  const unsigned short* Qb = Q + (size_t)bh * Ssz * HDsz;
  const unsigned short* Kb = Kg + (size_t)bh * Ssz * HDsz;
  const unsigned short* Vb = Vt + (size_t)bh * HDsz * Ssz;
  const int b = bh / Hn, h = bh % Hn;

  // read-side swizzle nibble for row = *16 + l15 (bit3 of row = l15>>3)
  const int hl = (l15 & 7) ^ ((l15 >> 3) << 2);
  // bpermute source-lane byte indices for the PV A-frag build
  const int sl0 = (l15 + ((lane >> 4) & 1) * 32) << 2;
  const int sl1 = sl0 + 64;
  const bool hiq = (quad >> 1) != 0;

  const int q0 = t * 128;
  const int rowStart = q0 + w * 32;

  bf16x8 qf[2][2];
#pragma unroll
  for (int tm = 0; tm < 2; tm++)
#pragma unroll
    for (int ks = 0; ks < 2; ks++)
      qf[tm][ks] = *reinterpret_cast<const bf16x8*>(
          &Qb[(size_t)(rowStart + tm * 16 + l15) * HDsz + ks * 32 + quad * 8]);

  f32x4 oacc[2][4];
  float lpart[2] = {0.f, 0.f};
#pragma unroll
  for (int tm = 0; tm < 2; tm++)
#pragma unroll
    for (int tn = 0; tn < 4; tn++) oacc[tm][tn] = (f32x4){0.f, 0.f, 0.f, 0.f};

  const int nkb = 2 * t + 2;
  for (int kb = 0; kb < nkb; kb++) {
    const int kv0 = kb * 64;
#pragma unroll
    for (int i = 0; i < 2; i++) {
      const int r8 = w * 16 + i * 8;
      const int sc = (((lane & 7) ^ rr ^ (i << 2))) * 8;
      async_cp16(&Kb[(size_t)(kv0 + r8 + rr) * HDsz + sc], &Ks[r8 * 64]);
      async_cp16(&Vb[(size_t)(r8 + rr) * Ssz + kv0 + sc], &Vs[r8 * 64]);
    }
    __syncthreads();

    const bool skip = (kv0 >= rowStart + 32);  // wave-uniform: fully masked
    if (!skip) {
      // S^T = K Q^T : sc[tn][tm], lane holds q=l15, kv=quad*4+r
      f32x4 sc[4][2];
#pragma unroll
      for (int tn = 0; tn < 4; tn++)
#pragma unroll
        for (int tm = 0; tm < 2; tm++) sc[tn][tm] = (f32x4){0.f, 0.f, 0.f, 0.f};
#pragma unroll
      for (int ks = 0; ks < 2; ks++) {
#pragma unroll
        for (int tn = 0; tn < 4; tn++) {
          const int rk = tn * 16 + l15;
          bf16x8 kf = *reinterpret_cast<const bf16x8*>(
              &Ks[rk * 64 + (((ks * 4 + quad) ^ hl) * 8)]);
#pragma unroll
          for (int tm = 0; tm < 2; tm++)
            sc[tn][tm] = MFMA32(kf, qf[tm][ks], sc[tn][tm]);
        }
      }

      const bool needMask = (kv0 + 63 > rowStart);  // wave-uniform
      if (needMask) {
#pragma unroll
        for (int tn = 0; tn < 4; tn++)
#pragma unroll
          for (int tm = 0; tm < 2; tm++) {
            const int qrow = rowStart + tm * 16 + l15;
#pragma unroll
            for (int r = 0; r < 4; r++)
              if (kv0 + tn * 16 + quad * 4 + r > qrow) sc[tn][tm][r] = -1e30f;
          }
      }

      // p = exp2(s) (Q pre-scaled by log2e/8; no max: s <= ~9)
      // pk[tn][tm][m] = bf16 pair (r=2m, r=2m+1) at kv = tn*16 + quad*4 + 2m
      unsigned int pk[4][2][2];
#pragma unroll
      for (int tn = 0; tn < 4; tn++)
#pragma unroll
        for (int tm = 0; tm < 2; tm++) {
          union { float f; unsigned int u; } e0, e1, e2, e3;
          e0.f = __builtin_amdgcn_exp2f(sc[tn][tm][0]);
          e1.f = __builtin_amdgcn_exp2f(sc[tn][tm][1]);
          e2.f = __builtin_amdgcn_exp2f(sc[tn][tm][2]);
          e3.f = __builtin_amdgcn_exp2f(sc[tn][tm][3]);
          lpart[tm] += (e0.f + e1.f) + (e2.f + e3.f);
          pk[tn][tm][0] = __builtin_amdgcn_perm(e1.u, e0.u, 0x07060302u);
          pk[tn][tm][1] = __builtin_amdgcn_perm(e3.u, e2.u, 0x07060302u);
        }

      // O += P V via K=32 MFMA: A-frag by cross-quad bpermute, V as b128.
#pragma unroll
      for (int C = 0; C < 2; C++) {  // kv 32-chunk
        bf16x8 pa32[2];
#pragma unroll
        for (int tm = 0; tm < 2; tm++) {
          union { unsigned int u[4]; bf16x8 v; } cv;
#pragma unroll
          for (int m = 0; m < 4; m++) {
            const int sl = (m < 2) ? sl0 : sl1;
            const int mm = m & 1;
            const int lo = __builtin_amdgcn_ds_bpermute(sl, (int)pk[2 * C][tm][mm]);
            const int hi = __builtin_amdgcn_ds_bpermute(sl, (int)pk[2 * C + 1][tm][mm]);
            cv.u[m] = (unsigned int)(hiq ? hi : lo);
          }
          pa32[tm] = cv.v;
        }
#pragma unroll
        for (int to = 0; to < 4; to++) {  // hd tiles
          const int rv = to * 16 + l15;
          const int c8 = C * 4 + quad;  // 8-bf16 chunk along kv
          bf16x8 vf = *reinterpret_cast<const bf16x8*>(
              (const char*)Vs + rv * 128 + ((c8 ^ hl) * 16));
#pragma unroll
          for (int tm = 0; tm < 2; tm++)
            oacc[tm][to] = MFMA32(pa32[tm], vf, oacc[tm][to]);
        }
      }
    }
    __syncthreads();
  }

  // l: reduce across quads (partials live at q=l15), redistribute to
  // C-layout rows (q=quad*4+r) via bpermute; normalize and store.
#pragma unroll
  for (int tm = 0; tm < 2; tm++) {
    float lf = lpart[tm];
    lf += __shfl_xor(lf, 16);
    lf += __shfl_xor(lf, 32);
    float linv[4];
#pragma unroll
    for (int r = 0; r < 4; r++) {
      union { float f; int i; } cv;
      cv.f = lf;
      cv.i = __builtin_amdgcn_ds_bpermute((quad * 4 + r) * 4, cv.i);
      linv[r] = 1.f / cv.f;
    }
#pragma unroll
    for (int r = 0; r < 4; r++) {
      const int s = rowStart + tm * 16 + quad * 4 + r;
      const size_t m = (size_t)b * Ssz + s;
#pragma unroll
      for (int tn = 0; tn < 4; tn++) {
        const int n = h * HDsz + tn * 16 + l15;
        AO[m * Dsz + n] = f2bf(oacc[tm][tn][r] * linv[r]);
      }
    }
  }
}

extern "C" void kernel_launch(void* const* d_in, const int* in_sizes, int n_in,
                              void* d_out, int out_size, void* d_ws, size_t ws_size,
                              hipStream_t stream) {
  const float* x  = (const float*)d_in[0];
  const float* Wq = (const float*)d_in[1];
  const float* Wk = (const float*)d_in[2];
  const float* Wv = (const float*)d_in[3];
  const float* Wo = (const float*)d_in[4];
  const float* bo = (const float*)d_in[5];
  float* out = (float*)d_out;

  unsigned short* xb  = (unsigned short*)d_ws;
  unsigned short* Wqt = xb + (size_t)Msz * Dsz;   // Wqt/Wkt/Wvt consecutive = concat [3072][1024]
  unsigned short* Wkt = Wqt + (size_t)Dsz * Dsz;
  unsigned short* Wvt = Wkt + (size_t)Dsz * Dsz;
  unsigned short* Wot = Wvt + (size_t)Dsz * Dsz;
  unsigned short* Qh  = Wot + (size_t)Dsz * Dsz;
  unsigned short* Kh  = Qh + (size_t)Msz * Dsz;
  unsigned short* Vth = Kh + (size_t)Msz * Dsz;
  unsigned short* AO  = Vth + (size_t)Msz * Dsz;

  prep_kernel<<<dim3(32, 32, 5), 256, 0, stream>>>(
      x, xb, Wq, Wk, Wv, Wo, Wqt, Wkt, Wvt, Wot);

  // fused QKV projection: N = 3072 (proven 128x128 structure + XCD swizzle)
  gemm_bk64<EPI_QKV><<<dim3(3 * Dsz / 128, Msz / 128), 512, 0, stream>>>(
      xb, Wqt, Qh, Kh, Vth, nullptr, nullptr);

  flash_kernel<<<dim3(16, Bsz * Hn), 256, 0, stream>>>(Qh, Kh, Vth, AO);

  gemm_bk64<EPI_OUT><<<dim3(Dsz / 128, Msz / 128), 512, 0, stream>>>(
      AO, Wot, nullptr, nullptr, nullptr, out, bo);
}

// Round 6
// 240.809 us; speedup vs baseline: 1.0011x; 1.0011x over previous
//
#include <hip/hip_runtime.h>
#include <cstdint>
#include <cstddef>

typedef __attribute__((ext_vector_type(8))) short bf16x8;
typedef __attribute__((ext_vector_type(4))) short bf16x4;
typedef __attribute__((ext_vector_type(4))) float f32x4;

constexpr int Bsz = 4, Ssz = 2048, Dsz = 1024, Hn = 16, HDsz = 64;
constexpr int Msz = Bsz * Ssz; // 8192 rows of x
constexpr float LOG2E = 1.4426950408889634f;

// NOTE: do NOT gate amdgcn builtins with __has_builtin — it returns false
// in the HIP host pass.
#define MFMA16(a, b, c) __builtin_amdgcn_mfma_f32_16x16x16bf16_1k(a, b, c, 0, 0, 0)
#define MFMA32(a, b, c) __builtin_amdgcn_mfma_f32_16x16x32_bf16(a, b, c, 0, 0, 0)

__device__ __forceinline__ unsigned short f2bf(float f) {
  union { float f; unsigned int u; } v; v.f = f;
  unsigned int r = v.u + 0x7fffu + ((v.u >> 16) & 1u);
  return (unsigned short)(r >> 16);
}

// async 16B global -> LDS (wave-uniform LDS base + lane*16)
typedef __attribute__((address_space(1))) const unsigned int gu32;
typedef __attribute__((address_space(3))) unsigned int lu32;
__device__ __forceinline__ void async_cp16(const unsigned short* g, unsigned short* l) {
  __builtin_amdgcn_global_load_lds((gu32*)g, (lu32*)l, 16, 0, 0);
}

// ---------- fused: 4x W-transpose (z=0..3) + x fp32->bf16 (z=4) ----------
__global__ void prep_kernel(const float* __restrict__ x, unsigned short* __restrict__ xb,
                            const float* __restrict__ W0, const float* __restrict__ W1,
                            const float* __restrict__ W2, const float* __restrict__ W3,
                            unsigned short* __restrict__ T0, unsigned short* __restrict__ T1,
                            unsigned short* __restrict__ T2, unsigned short* __restrict__ T3) {
  const int z = blockIdx.z;
  if (z == 4) {  // x convert: 1024 blocks x 256 thr x 8 float4
    const int i0 = (blockIdx.y * 32 + blockIdx.x) * 2048 + threadIdx.x;
#pragma unroll
    for (int j = 0; j < 8; j++) {
      const int i = i0 + j * 256;
      const float4 v = reinterpret_cast<const float4*>(x)[i];
      ushort4 o;
      o.x = f2bf(v.x); o.y = f2bf(v.y); o.z = f2bf(v.z); o.w = f2bf(v.w);
      reinterpret_cast<ushort4*>(xb)[i] = o;
    }
    return;
  }
  __shared__ float tile[32][33];
  const float* W = (z == 0) ? W0 : (z == 1) ? W1 : (z == 2) ? W2 : W3;
  unsigned short* Wt = (z == 0) ? T0 : (z == 1) ? T1 : (z == 2) ? T2 : T3;
  int tx = threadIdx.x & 31, ty = threadIdx.x >> 5; // 32 x 8
  int bx = blockIdx.x, by = blockIdx.y;
#pragma unroll
  for (int i = 0; i < 4; i++) {
    int k = by * 32 + ty + i * 8;
    tile[ty + i * 8][tx] = W[k * Dsz + bx * 32 + tx];
  }
  __syncthreads();
#pragma unroll
  for (int i = 0; i < 4; i++) {
    int nrow = bx * 32 + ty + i * 8;
    Wt[nrow * Dsz + by * 32 + tx] = f2bf(tile[tx][ty + i * 8]);
  }
}

// ---------- 128x128-tile, BK=64, 512 threads (8 waves, 32x64 acc/wave) ----------
// XOR-swizzled async-staged bf16 GEMM, C = A[M,K] * Bt[N,K]^T.
// bm-chunked bijective XCD swizzle (verified r2: FETCH 103->41MB; r4 here:
// 76.8->49.2MB): XCD x owns bm in [8x,8x+8) x all bn -> per-XCD A = 2MB
// (L2-resident), B panel shared via L3.
enum { EPI_QKV = 0, EPI_OUT = 1 };

template <int EPI>
__global__ __launch_bounds__(512, 4)
void gemm_bk64(const unsigned short* __restrict__ A,
               const unsigned short* __restrict__ Bt,
               unsigned short* __restrict__ Qh,
               unsigned short* __restrict__ Kh,
               unsigned short* __restrict__ Vth,
               float* __restrict__ Out,
               const float* __restrict__ bias) {
  __shared__ unsigned short As[128 * 64];
  __shared__ unsigned short Bs[128 * 64];

  const int tid = threadIdx.x;
  const int w = tid >> 6, lane = tid & 63;
  const int l15 = lane & 15, quad = lane >> 4;
  const int wr = w >> 1, wc = w & 1;
  const int orig = blockIdx.y * gridDim.x + blockIdx.x;
  const int xcd = orig & 7, idx = orig >> 3;
  const int bm = (xcd << 3) | (idx & 7);
  const int bn = idx >> 3;
  const int rr = lane >> 3;                 // row within 8-row group
  const int scoff = ((lane & 7) ^ rr) * 8;  // swizzled source col (shorts)

  f32x4 acc[2][4];
#pragma unroll
  for (int i = 0; i < 2; i++)
#pragma unroll
    for (int j = 0; j < 4; j++) acc[i][j] = (f32x4){0.f, 0.f, 0.f, 0.f};

  const int rowA0 = bm * 128, rowB0 = bn * 128;

  for (int kt = 0; kt < Dsz / 64; kt++) {
#pragma unroll
    for (int i = 0; i < 2; i++) {
      const int r8 = w * 16 + i * 8;
      async_cp16(&A[(size_t)(rowA0 + r8 + rr) * Dsz + kt * 64 + scoff], &As[r8 * 64]);
      async_cp16(&Bt[(size_t)(rowB0 + r8 + rr) * Dsz + kt * 64 + scoff], &Bs[r8 * 64]);
    }
    __syncthreads();

#pragma unroll
    for (int ks = 0; ks < 2; ks++) {
      bf16x8 af[2], bfr[4];
#pragma unroll
      for (int t = 0; t < 2; t++) {
        const int ra = wr * 32 + t * 16 + l15;
        af[t] = *reinterpret_cast<const bf16x8*>(
            &As[ra * 64 + (((ks * 4 + quad) ^ (ra & 7)) * 8)]);
      }
#pragma unroll
      for (int t = 0; t < 4; t++) {
        const int rb = wc * 64 + t * 16 + l15;
        bfr[t] = *reinterpret_cast<const bf16x8*>(
            &Bs[rb * 64 + (((ks * 4 + quad) ^ (rb & 7)) * 8)]);
      }
#pragma unroll
      for (int i = 0; i < 2; i++)
#pragma unroll
        for (int j = 0; j < 4; j++)
          acc[i][j] = MFMA32(af[i], bfr[j], acc[i][j]);
    }
    __syncthreads();
  }

  if (EPI == EPI_QKV) {
    const int proj = (bn * 128) >> 10;  // block-uniform: 0=Q 1=K 2=V
#pragma unroll
    for (int i = 0; i < 2; i++) {
#pragma unroll
      for (int j = 0; j < 4; j++) {
        const int n = bn * 128 + wc * 64 + j * 16 + l15;
        const int nn = n & 1023, h = nn >> 6, hd = nn & 63;
        const int m0 = bm * 128 + wr * 32 + i * 16 + quad * 4;
        const int b = m0 >> 11, s0 = m0 & (Ssz - 1);
        if (proj == 0) {
#pragma unroll
          for (int r = 0; r < 4; r++)
            Qh[((size_t)(b * Hn + h) * Ssz + s0 + r) * HDsz + hd] =
                f2bf(acc[i][j][r] * (0.125f * LOG2E));
        } else if (proj == 1) {
#pragma unroll
          for (int r = 0; r < 4; r++)
            Kh[((size_t)(b * Hn + h) * Ssz + s0 + r) * HDsz + hd] = f2bf(acc[i][j][r]);
        } else {
          ushort4 o;
          o.x = f2bf(acc[i][j][0]); o.y = f2bf(acc[i][j][1]);
          o.z = f2bf(acc[i][j][2]); o.w = f2bf(acc[i][j][3]);
          *reinterpret_cast<ushort4*>(
              &Vth[((size_t)(b * Hn + h) * HDsz + hd) * Ssz + s0]) = o;
        }
      }
    }
  } else {
#pragma unroll
    for (int i = 0; i < 2; i++) {
#pragma unroll
      for (int j = 0; j < 4; j++) {
        const int n = bn * 128 + wc * 64 + j * 16 + l15;
        const int m0 = bm * 128 + wr * 32 + i * 16 + quad * 4;
#pragma unroll
        for (int r = 0; r < 4; r++)
          Out[(size_t)(m0 + r) * Dsz + n] = acc[i][j][r] + bias[n];
      }
    }
  }
}

// ---------- flash attention: 64-row q-tiles, 8 blocks/CU for full TLP ----------
// ROUND-6 CHANGE (occupancy): r4 counters showed MFMA 30% + VALU 36% + HBM 10%
// + conflicts 0 at 4 blocks/CU -> latency-bound, no pipe saturated. Halve the
// q-tile to 64 rows (16/wave), double the grid to 2048 blocks = 8 blocks/CU
// (32 waves, full occupancy). PV stays on the zero-shuffle MFMA16 path (r5:
// the MFMA32-PV bpermute build cost 8.65e6 crossbar-conflict cycles — src
// lanes {0-15,32-47} = 4 readers/mod-32 class — netting a loss).
// Balance: co-resident blocks share c = linear%256 -> same bh (K/V 512KB
// L2-resident per XCD, since linear%8 = XCD is bh-constant) and t-set
// {8r+k, 31-8r-k : k=0..3} -> exactly 132 kv-iters per CU for every r.
// 4-bit storage swizzle h = (row&7)^(((row>>3)&1)<<2) as before.
__global__ __launch_bounds__(256, 8)
void flash_kernel(const unsigned short* __restrict__ Q,
                  const unsigned short* __restrict__ Kg,
                  const unsigned short* __restrict__ Vt,
                  unsigned short* __restrict__ AO) {
  __shared__ unsigned short Ks[64 * 64];
  __shared__ unsigned short Vs[64 * 64];

  const int tid = threadIdx.x;
  const int w = tid >> 6, lane = tid & 63;
  const int l15 = lane & 15, quad = lane >> 4;
  const int rr = lane >> 3;

  const int linear = blockIdx.y * 16 + blockIdx.x;  // grid (16,128) = 2048
  const int bh = (linear & 7) * 8 + ((linear >> 3) & 7);
  const int g = linear >> 6;            // 0..31
  const int gk = g >> 2, gr = g & 3;    // co-resident: gk = 0..7, gr fixed
  const int t = (gk < 4) ? (gr * 8 + gk) : (31 - (gr * 8 + (gk - 4)));

  const unsigned short* Qb = Q + (size_t)bh * Ssz * HDsz;
  const unsigned short* Kb = Kg + (size_t)bh * Ssz * HDsz;
  const unsigned short* Vb = Vt + (size_t)bh * HDsz * Ssz;
  const int b = bh / Hn, h = bh % Hn;

  // read-side swizzle nibble for row = *16 + l15 (bit3 of row = l15>>3)
  const int hl = (l15 & 7) ^ ((l15 >> 3) << 2);

  const int q0 = t * 64;
  const int rowStart = q0 + w * 16;

  bf16x8 qf[2];
#pragma unroll
  for (int ks = 0; ks < 2; ks++)
    qf[ks] = *reinterpret_cast<const bf16x8*>(
        &Qb[(size_t)(rowStart + l15) * HDsz + ks * 32 + quad * 8]);

  f32x4 oacc[4];
  float lpart = 0.f;
#pragma unroll
  for (int to = 0; to < 4; to++) oacc[to] = (f32x4){0.f, 0.f, 0.f, 0.f};

  const int nkb = t + 1;
  for (int kb = 0; kb < nkb; kb++) {
    const int kv0 = kb * 64;
#pragma unroll
    for (int i = 0; i < 2; i++) {
      const int r8 = w * 16 + i * 8;
      const int sc = (((lane & 7) ^ rr ^ (i << 2))) * 8;
      async_cp16(&Kb[(size_t)(kv0 + r8 + rr) * HDsz + sc], &Ks[r8 * 64]);
      async_cp16(&Vb[(size_t)(r8 + rr) * Ssz + kv0 + sc], &Vs[r8 * 64]);
    }
    __syncthreads();

    // S^T = K Q^T : sc[tn], lane holds q=l15, kv=tn*16+quad*4+r
    f32x4 sc[4];
#pragma unroll
    for (int tn = 0; tn < 4; tn++) sc[tn] = (f32x4){0.f, 0.f, 0.f, 0.f};
#pragma unroll
    for (int ks = 0; ks < 2; ks++) {
#pragma unroll
      for (int tn = 0; tn < 4; tn++) {
        const int rk = tn * 16 + l15;
        bf16x8 kf = *reinterpret_cast<const bf16x8*>(
            &Ks[rk * 64 + (((ks * 4 + quad) ^ hl) * 8)]);
        sc[tn] = MFMA32(kf, qf[ks], sc[tn]);
      }
    }

    const bool needMask = (kv0 + 63 > rowStart);  // wave-uniform
    if (needMask) {
      const int qrow = rowStart + l15;
#pragma unroll
      for (int tn = 0; tn < 4; tn++)
#pragma unroll
        for (int r = 0; r < 4; r++)
          if (kv0 + tn * 16 + quad * 4 + r > qrow) sc[tn][r] = -1e30f;
    }

    // p = exp2(s) (Q pre-scaled by log2e/8; no max: s <= ~9)
    unsigned int pk[4][2];
#pragma unroll
    for (int tn = 0; tn < 4; tn++) {
      union { float f; unsigned int u; } e0, e1, e2, e3;
      e0.f = __builtin_amdgcn_exp2f(sc[tn][0]);
      e1.f = __builtin_amdgcn_exp2f(sc[tn][1]);
      e2.f = __builtin_amdgcn_exp2f(sc[tn][2]);
      e3.f = __builtin_amdgcn_exp2f(sc[tn][3]);
      lpart += (e0.f + e1.f) + (e2.f + e3.f);
      pk[tn][0] = __builtin_amdgcn_perm(e1.u, e0.u, 0x07060302u);
      pk[tn][1] = __builtin_amdgcn_perm(e3.u, e2.u, 0x07060302u);
    }

    // O += P V : 4 k=16 steps; V-frags (b64), zero-shuffle layout match
#pragma unroll
    for (int tn = 0; tn < 4; tn++) {  // k-step over kv
      union { unsigned int u[2]; bf16x4 v; } cv;
      cv.u[0] = pk[tn][0]; cv.u[1] = pk[tn][1];
      const bf16x4 pa = cv.v;
#pragma unroll
      for (int to = 0; to < 4; to++) {  // hd tiles
        const int rv = to * 16 + l15;
        const int chunk = tn * 2 + (quad >> 1);
        bf16x4 vf = *reinterpret_cast<const bf16x4*>(
            (const char*)Vs + rv * 128 + ((chunk ^ hl) * 16) + (quad & 1) * 8);
        oacc[to] = MFMA16(pa, vf, oacc[to]);
      }
    }
    __syncthreads();
  }

  // l: reduce across quads (partials live at q=l15), redistribute to
  // C-layout rows (q=quad*4+r) via bpermute; normalize and store.
  float lf = lpart;
  lf += __shfl_xor(lf, 16);
  lf += __shfl_xor(lf, 32);
  float linv[4];
#pragma unroll
  for (int r = 0; r < 4; r++) {
    union { float f; int i; } cv;
    cv.f = lf;
    cv.i = __builtin_amdgcn_ds_bpermute((quad * 4 + r) * 4, cv.i);
    linv[r] = 1.f / cv.f;
  }
#pragma unroll
  for (int r = 0; r < 4; r++) {
    const int s = rowStart + quad * 4 + r;
    const size_t m = (size_t)b * Ssz + s;
#pragma unroll
    for (int to = 0; to < 4; to++) {
      const int n = h * HDsz + to * 16 + l15;
      AO[m * Dsz + n] = f2bf(oacc[to][r] * linv[r]);
    }
  }
}

extern "C" void kernel_launch(void* const* d_in, const int* in_sizes, int n_in,
                              void* d_out, int out_size, void* d_ws, size_t ws_size,
                              hipStream_t stream) {
  const float* x  = (const float*)d_in[0];
  const float* Wq = (const float*)d_in[1];
  const float* Wk = (const float*)d_in[2];
  const float* Wv = (const float*)d_in[3];
  const float* Wo = (const float*)d_in[4];
  const float* bo = (const float*)d_in[5];
  float* out = (float*)d_out;

  unsigned short* xb  = (unsigned short*)d_ws;
  unsigned short* Wqt = xb + (size_t)Msz * Dsz;   // Wqt/Wkt/Wvt consecutive = concat [3072][1024]
  unsigned short* Wkt = Wqt + (size_t)Dsz * Dsz;
  unsigned short* Wvt = Wkt + (size_t)Dsz * Dsz;
  unsigned short* Wot = Wvt + (size_t)Dsz * Dsz;
  unsigned short* Qh  = Wot + (size_t)Dsz * Dsz;
  unsigned short* Kh  = Qh + (size_t)Msz * Dsz;
  unsigned short* Vth = Kh + (size_t)Msz * Dsz;
  unsigned short* AO  = Vth + (size_t)Msz * Dsz;

  prep_kernel<<<dim3(32, 32, 5), 256, 0, stream>>>(
      x, xb, Wq, Wk, Wv, Wo, Wqt, Wkt, Wvt, Wot);

  // fused QKV projection: N = 3072 (proven 128x128 structure + XCD swizzle)
  gemm_bk64<EPI_QKV><<<dim3(3 * Dsz / 128, Msz / 128), 512, 0, stream>>>(
      xb, Wqt, Qh, Kh, Vth, nullptr, nullptr);

  flash_kernel<<<dim3(16, 128), 256, 0, stream>>>(Qh, Kh, Vth, AO);

  gemm_bk64<EPI_OUT><<<dim3(Dsz / 128, Msz / 128), 512, 0, stream>>>(
      AO, Wot, nullptr, nullptr, nullptr, out, bo);
}

// Round 7
// 227.308 us; speedup vs baseline: 1.0606x; 1.0594x over previous
//
#include <hip/hip_runtime.h>
#include <cstdint>
#include <cstddef>

typedef __attribute__((ext_vector_type(8))) short bf16x8;
typedef __attribute__((ext_vector_type(4))) float f32x4;
typedef __attribute__((ext_vector_type(16))) float f32x16;

constexpr int Bsz = 4, Ssz = 2048, Dsz = 1024, Hn = 16, HDsz = 64;
constexpr int Msz = Bsz * Ssz; // 8192 rows of x
constexpr float LOG2E = 1.4426950408889634f;

// NOTE: do NOT gate amdgcn builtins with __has_builtin — it returns false
// in the HIP host pass.
#define MFMA32(a, b, c) __builtin_amdgcn_mfma_f32_16x16x32_bf16(a, b, c, 0, 0, 0)
#define MFMA3232(a, b, c) __builtin_amdgcn_mfma_f32_32x32x16_bf16(a, b, c, 0, 0, 0)

__device__ __forceinline__ unsigned short f2bf(float f) {
  union { float f; unsigned int u; } v; v.f = f;
  unsigned int r = v.u + 0x7fffu + ((v.u >> 16) & 1u);
  return (unsigned short)(r >> 16);
}

// v_cvt_pk_bf16_f32: dst = {lo: bf16(a), hi: bf16(b)} (T12 recipe, no builtin)
__device__ __forceinline__ int cvtpk(float a, float b) {
  int r;
  asm("v_cvt_pk_bf16_f32 %0, %1, %2" : "=v"(r) : "v"(a), "v"(b));
  return r;
}
// v_permlane32_swap_b32: a.hi-lanes <-> b.lo-lanes. After:
//   a(lane<32)=a, a(lane>=32)=b(lane-32);  b(lane<32)=a(lane+32), b(lane>=32)=b.
__device__ __forceinline__ void pswap(int& a, int& b) {
  asm("v_permlane32_swap_b32 %0, %1" : "+v"(a), "+v"(b));
}

// async 16B global -> LDS (wave-uniform LDS base + lane*16)
typedef __attribute__((address_space(1))) const unsigned int gu32;
typedef __attribute__((address_space(3))) unsigned int lu32;
__device__ __forceinline__ void async_cp16(const unsigned short* g, unsigned short* l) {
  __builtin_amdgcn_global_load_lds((gu32*)g, (lu32*)l, 16, 0, 0);
}

// ---------- fused: 4x W-transpose (z=0..3) + x fp32->bf16 (z=4) ----------
__global__ void prep_kernel(const float* __restrict__ x, unsigned short* __restrict__ xb,
                            const float* __restrict__ W0, const float* __restrict__ W1,
                            const float* __restrict__ W2, const float* __restrict__ W3,
                            unsigned short* __restrict__ T0, unsigned short* __restrict__ T1,
                            unsigned short* __restrict__ T2, unsigned short* __restrict__ T3) {
  const int z = blockIdx.z;
  if (z == 4) {  // x convert: 1024 blocks x 256 thr x 8 float4
    const int i0 = (blockIdx.y * 32 + blockIdx.x) * 2048 + threadIdx.x;
#pragma unroll
    for (int j = 0; j < 8; j++) {
      const int i = i0 + j * 256;
      const float4 v = reinterpret_cast<const float4*>(x)[i];
      ushort4 o;
      o.x = f2bf(v.x); o.y = f2bf(v.y); o.z = f2bf(v.z); o.w = f2bf(v.w);
      reinterpret_cast<ushort4*>(xb)[i] = o;
    }
    return;
  }
  __shared__ float tile[32][33];
  const float* W = (z == 0) ? W0 : (z == 1) ? W1 : (z == 2) ? W2 : W3;
  unsigned short* Wt = (z == 0) ? T0 : (z == 1) ? T1 : (z == 2) ? T2 : T3;
  int tx = threadIdx.x & 31, ty = threadIdx.x >> 5; // 32 x 8
  int bx = blockIdx.x, by = blockIdx.y;
#pragma unroll
  for (int i = 0; i < 4; i++) {
    int k = by * 32 + ty + i * 8;
    tile[ty + i * 8][tx] = W[k * Dsz + bx * 32 + tx];
  }
  __syncthreads();
#pragma unroll
  for (int i = 0; i < 4; i++) {
    int nrow = bx * 32 + ty + i * 8;
    Wt[nrow * Dsz + by * 32 + tx] = f2bf(tile[tx][ty + i * 8]);
  }
}

// ---------- 128x128-tile, BK=64, 512 threads (8 waves, 32x64 acc/wave) ----------
// XOR-swizzled async-staged bf16 GEMM, C = A[M,K] * Bt[N,K]^T.
// bm-chunked bijective XCD swizzle (verified r2: FETCH 103->41MB; r4 here:
// 76.8->49.2MB): XCD x owns bm in [8x,8x+8) x all bn -> per-XCD A = 2MB
// (L2-resident), B panel shared via L3.
enum { EPI_QKV = 0, EPI_OUT = 1 };

template <int EPI>
__global__ __launch_bounds__(512, 4)
void gemm_bk64(const unsigned short* __restrict__ A,
               const unsigned short* __restrict__ Bt,
               unsigned short* __restrict__ Qh,
               unsigned short* __restrict__ Kh,
               unsigned short* __restrict__ Vth,
               float* __restrict__ Out,
               const float* __restrict__ bias) {
  __shared__ unsigned short As[128 * 64];
  __shared__ unsigned short Bs[128 * 64];

  const int tid = threadIdx.x;
  const int w = tid >> 6, lane = tid & 63;
  const int l15 = lane & 15, quad = lane >> 4;
  const int wr = w >> 1, wc = w & 1;
  const int orig = blockIdx.y * gridDim.x + blockIdx.x;
  const int xcd = orig & 7, idx = orig >> 3;
  const int bm = (xcd << 3) | (idx & 7);
  const int bn = idx >> 3;
  const int rr = lane >> 3;                 // row within 8-row group
  const int scoff = ((lane & 7) ^ rr) * 8;  // swizzled source col (shorts)

  f32x4 acc[2][4];
#pragma unroll
  for (int i = 0; i < 2; i++)
#pragma unroll
    for (int j = 0; j < 4; j++) acc[i][j] = (f32x4){0.f, 0.f, 0.f, 0.f};

  const int rowA0 = bm * 128, rowB0 = bn * 128;

  for (int kt = 0; kt < Dsz / 64; kt++) {
#pragma unroll
    for (int i = 0; i < 2; i++) {
      const int r8 = w * 16 + i * 8;
      async_cp16(&A[(size_t)(rowA0 + r8 + rr) * Dsz + kt * 64 + scoff], &As[r8 * 64]);
      async_cp16(&Bt[(size_t)(rowB0 + r8 + rr) * Dsz + kt * 64 + scoff], &Bs[r8 * 64]);
    }
    __syncthreads();

#pragma unroll
    for (int ks = 0; ks < 2; ks++) {
      bf16x8 af[2], bfr[4];
#pragma unroll
      for (int t = 0; t < 2; t++) {
        const int ra = wr * 32 + t * 16 + l15;
        af[t] = *reinterpret_cast<const bf16x8*>(
            &As[ra * 64 + (((ks * 4 + quad) ^ (ra & 7)) * 8)]);
      }
#pragma unroll
      for (int t = 0; t < 4; t++) {
        const int rb = wc * 64 + t * 16 + l15;
        bfr[t] = *reinterpret_cast<const bf16x8*>(
            &Bs[rb * 64 + (((ks * 4 + quad) ^ (rb & 7)) * 8)]);
      }
#pragma unroll
      for (int i = 0; i < 2; i++)
#pragma unroll
        for (int j = 0; j < 4; j++)
          acc[i][j] = MFMA32(af[i], bfr[j], acc[i][j]);
    }
    __syncthreads();
  }

  if (EPI == EPI_QKV) {
    const int proj = (bn * 128) >> 10;  // block-uniform: 0=Q 1=K 2=V
#pragma unroll
    for (int i = 0; i < 2; i++) {
#pragma unroll
      for (int j = 0; j < 4; j++) {
        const int n = bn * 128 + wc * 64 + j * 16 + l15;
        const int nn = n & 1023, h = nn >> 6, hd = nn & 63;
        const int m0 = bm * 128 + wr * 32 + i * 16 + quad * 4;
        const int b = m0 >> 11, s0 = m0 & (Ssz - 1);
        if (proj == 0) {
#pragma unroll
          for (int r = 0; r < 4; r++)
            Qh[((size_t)(b * Hn + h) * Ssz + s0 + r) * HDsz + hd] =
                f2bf(acc[i][j][r] * (0.125f * LOG2E));
        } else if (proj == 1) {
#pragma unroll
          for (int r = 0; r < 4; r++)
            Kh[((size_t)(b * Hn + h) * Ssz + s0 + r) * HDsz + hd] = f2bf(acc[i][j][r]);
        } else {
          ushort4 o;
          o.x = f2bf(acc[i][j][0]); o.y = f2bf(acc[i][j][1]);
          o.z = f2bf(acc[i][j][2]); o.w = f2bf(acc[i][j][3]);
          *reinterpret_cast<ushort4*>(
              &Vth[((size_t)(b * Hn + h) * HDsz + hd) * Ssz + s0]) = o;
        }
      }
    }
  } else {
#pragma unroll
    for (int i = 0; i < 2; i++) {
#pragma unroll
      for (int j = 0; j < 4; j++) {
        const int n = bn * 128 + wc * 64 + j * 16 + l15;
        const int m0 = bm * 128 + wr * 32 + i * 16 + quad * 4;
#pragma unroll
        for (int r = 0; r < 4; r++)
          Out[(size_t)(m0 + r) * Dsz + n] = acc[i][j][r] + bias[n];
      }
    }
  }
}

// ---------- flash attention v7: 32x32 MFMA, swapped QK^T, in-reg softmax ----------
// Grid/t-perm/staging/LDS bytes identical to the proven r4 kernel (1024 blocks,
// 4/CU, 68 kv-iters/CU, storage swizzle h(row)=(row&7)^(((row>>3)&1)<<2)).
// ROUND-7 CHANGE (m214/T12 port): all MFMA on full-rate 32x32x16_bf16.
//  - S^T = mfma(K, Q): C col=q=lane&31, row=kv=(reg&3)+8*(reg>>2)+4*(lane>>5).
//  - softmax row-local: lpart per lane + shfl_xor(32) only.
//  - P->A-frag: per 16-kv step, 4 cvt_pk + 2 permlane32_swap:
//      swap(pk(p0,p1), pk(p4,p5)) -> A words 0,2; swap(pk(p2,p3),pk(p6,p7)) -> 1,3.
//  - PV = mfma(P, V): B-frag row=hd=lane&31, k-chunk (t16*2+hi)^h(row), b128.
// Removes the 1/4-rate _1k MFMA16 chain (r5-confirmed: ~620 cyc/iter) with
// zero LDS-shuffle cost. r4 kernel is the fallback if this regresses.
__global__ __launch_bounds__(256, 4)
void flash_kernel(const unsigned short* __restrict__ Q,
                  const unsigned short* __restrict__ Kg,
                  const unsigned short* __restrict__ Vt,
                  unsigned short* __restrict__ AO) {
  __shared__ unsigned short Ks[64 * 64];
  __shared__ unsigned short Vs[64 * 64];

  const int tid = threadIdx.x;
  const int w = tid >> 6, lane = tid & 63;
  const int l31 = lane & 31, hi = lane >> 5;
  const int rr = lane >> 3;

  const int linear = blockIdx.y * 16 + blockIdx.x;
  const int bh = (linear & 7) * 8 + ((linear >> 3) & 7);
  const int g = linear >> 6, gk = g >> 2, ga = g & 3;
  const int t = (gk == 0) ? 15 - ga : (gk == 1) ? 8 + ga : (gk == 2) ? 7 - ga : ga;

  const unsigned short* Qb = Q + (size_t)bh * Ssz * HDsz;
  const unsigned short* Kb = Kg + (size_t)bh * Ssz * HDsz;
  const unsigned short* Vb = Vt + (size_t)bh * HDsz * Ssz;
  const int b = bh / Hn, h = bh % Hn;

  // read-side swizzle nibble for rows kt*32+l31 / ho*32+l31 (row&7 = l31&7,
  // (row>>3)&1 = (l31>>3)&1 since the *32 offsets are even multiples of 8)
  const int hl = (l31 & 7) ^ (((l31 >> 3) & 1) << 2);

  const int rowStart = t * 128 + w * 32;
  const int q = rowStart + l31;  // this lane's q-row (both halves share it)

  // Q as QK^T B-operand: col=q=lane&31, k = d = ks*16 + hi*8 + j
  bf16x8 qf[4];
#pragma unroll
  for (int ks = 0; ks < 4; ks++)
    qf[ks] = *reinterpret_cast<const bf16x8*>(
        &Qb[(size_t)q * HDsz + ks * 16 + hi * 8]);

  f32x16 oacc[2];
#pragma unroll
  for (int ho = 0; ho < 2; ho++)
#pragma unroll
    for (int r = 0; r < 16; r++) oacc[ho][r] = 0.f;
  float lpart = 0.f;

  const int nkb = 2 * t + 2;
  for (int kb = 0; kb < nkb; kb++) {
    const int kv0 = kb * 64;
#pragma unroll
    for (int i = 0; i < 2; i++) {
      const int r8 = w * 16 + i * 8;
      const int sc = (((lane & 7) ^ rr ^ (i << 2))) * 8;
      async_cp16(&Kb[(size_t)(kv0 + r8 + rr) * HDsz + sc], &Ks[r8 * 64]);
      async_cp16(&Vb[(size_t)(r8 + rr) * Ssz + kv0 + sc], &Vs[r8 * 64]);
    }
    __syncthreads();

#pragma unroll
    for (int kt = 0; kt < 2; kt++) {
      const bool skip = (kv0 + kt * 32 >= rowStart + 32);  // wave-uniform
      if (skip) continue;

      // S^T tile [kv 32][q 32]: A = K (row=kv, k=d), B = Q
      f32x16 st;
#pragma unroll
      for (int r = 0; r < 16; r++) st[r] = 0.f;
#pragma unroll
      for (int ks = 0; ks < 4; ks++) {
        const int row = kt * 32 + l31;
        bf16x8 kf = *reinterpret_cast<const bf16x8*>(
            &Ks[row * 64 + (((ks * 2 + hi) ^ hl) * 8)]);
        st = MFMA3232(kf, qf[ks], st);
      }

      const bool needMask = (kv0 + kt * 32 + 31 > rowStart);  // wave-uniform
      if (needMask) {
#pragma unroll
        for (int r = 0; r < 16; r++) {
          const int kv = kv0 + kt * 32 + (r & 3) + 8 * (r >> 2) + 4 * hi;
          if (kv > q) st[r] = -1e30f;
        }
      }

      // p = exp2(s) (Q pre-scaled by log2e/8); lpart pairwise
      float e[16];
#pragma unroll
      for (int r = 0; r < 16; r++) e[r] = __builtin_amdgcn_exp2f(st[r]);
#pragma unroll
      for (int r = 0; r < 16; r += 4)
        lpart += (e[r] + e[r + 1]) + (e[r + 2] + e[r + 3]);

      // PV: per 16-kv step s, build A-frag via cvt_pk + permlane32_swap
#pragma unroll
      for (int s = 0; s < 2; s++) {
        int a0 = cvtpk(e[8 * s + 0], e[8 * s + 1]);
        int a1 = cvtpk(e[8 * s + 2], e[8 * s + 3]);
        int b0 = cvtpk(e[8 * s + 4], e[8 * s + 5]);
        int b1 = cvtpk(e[8 * s + 6], e[8 * s + 7]);
        pswap(a0, b0);  // -> words 0, 2
        pswap(a1, b1);  // -> words 1, 3
        union { int u[4]; bf16x8 v; } pa;
        pa.u[0] = a0; pa.u[1] = a1; pa.u[2] = b0; pa.u[3] = b1;
        const int t16 = kt * 2 + s;
#pragma unroll
        for (int ho = 0; ho < 2; ho++) {
          const int row = ho * 32 + l31;
          bf16x8 vf = *reinterpret_cast<const bf16x8*>(
              &Vs[row * 64 + (((t16 * 2 + hi) ^ hl) * 8)]);
          oacc[ho] = MFMA3232(pa.v, vf, oacc[ho]);
        }
      }
    }
    __syncthreads();
  }

  // normalize: lf(q=l31) full row sum; redistribute to reg-rows via bpermute
  float lf = lpart + __shfl_xor(lpart, 32);
  float linv[16];
#pragma unroll
  for (int r = 0; r < 16; r++) {
    const int qloc = (r & 3) + 8 * (r >> 2) + 4 * hi;
    union { float f; int i; } cv;
    cv.f = lf;
    cv.i = __builtin_amdgcn_ds_bpermute(qloc * 4, cv.i);
    linv[r] = 1.f / cv.f;
  }
#pragma unroll
  for (int r = 0; r < 16; r++) {
    const int qloc = (r & 3) + 8 * (r >> 2) + 4 * hi;
    const size_t m = (size_t)b * Ssz + rowStart + qloc;
#pragma unroll
    for (int ho = 0; ho < 2; ho++) {
      const int n = h * HDsz + ho * 32 + l31;
      AO[m * Dsz + n] = f2bf(oacc[ho][r] * linv[r]);
    }
  }
}

extern "C" void kernel_launch(void* const* d_in, const int* in_sizes, int n_in,
                              void* d_out, int out_size, void* d_ws, size_t ws_size,
                              hipStream_t stream) {
  const float* x  = (const float*)d_in[0];
  const float* Wq = (const float*)d_in[1];
  const float* Wk = (const float*)d_in[2];
  const float* Wv = (const float*)d_in[3];
  const float* Wo = (const float*)d_in[4];
  const float* bo = (const float*)d_in[5];
  float* out = (float*)d_out;

  unsigned short* xb  = (unsigned short*)d_ws;
  unsigned short* Wqt = xb + (size_t)Msz * Dsz;   // Wqt/Wkt/Wvt consecutive = concat [3072][1024]
  unsigned short* Wkt = Wqt + (size_t)Dsz * Dsz;
  unsigned short* Wvt = Wkt + (size_t)Dsz * Dsz;
  unsigned short* Wot = Wvt + (size_t)Dsz * Dsz;
  unsigned short* Qh  = Wot + (size_t)Dsz * Dsz;
  unsigned short* Kh  = Qh + (size_t)Msz * Dsz;
  unsigned short* Vth = Kh + (size_t)Msz * Dsz;
  unsigned short* AO  = Vth + (size_t)Msz * Dsz;

  prep_kernel<<<dim3(32, 32, 5), 256, 0, stream>>>(
      x, xb, Wq, Wk, Wv, Wo, Wqt, Wkt, Wvt, Wot);

  // fused QKV projection: N = 3072 (proven 128x128 structure + XCD swizzle)
  gemm_bk64<EPI_QKV><<<dim3(3 * Dsz / 128, Msz / 128), 512, 0, stream>>>(
      xb, Wqt, Qh, Kh, Vth, nullptr, nullptr);

  flash_kernel<<<dim3(16, Bsz * Hn), 256, 0, stream>>>(Qh, Kh, Vth, AO);

  gemm_bk64<EPI_OUT><<<dim3(Dsz / 128, Msz / 128), 512, 0, stream>>>(
      AO, Wot, nullptr, nullptr, nullptr, out, bo);
}

// Round 8
// 223.788 us; speedup vs baseline: 1.0773x; 1.0157x over previous
//
#include <hip/hip_runtime.h>
#include <cstdint>
#include <cstddef>

typedef __attribute__((ext_vector_type(8))) short bf16x8;
typedef __attribute__((ext_vector_type(4))) float f32x4;
typedef __attribute__((ext_vector_type(16))) float f32x16;

constexpr int Bsz = 4, Ssz = 2048, Dsz = 1024, Hn = 16, HDsz = 64;
constexpr int Msz = Bsz * Ssz; // 8192 rows of x
constexpr float LOG2E = 1.4426950408889634f;

// NOTE: do NOT gate amdgcn builtins with __has_builtin — it returns false
// in the HIP host pass.
#define MFMA32(a, b, c) __builtin_amdgcn_mfma_f32_16x16x32_bf16(a, b, c, 0, 0, 0)
#define MFMA3232(a, b, c) __builtin_amdgcn_mfma_f32_32x32x16_bf16(a, b, c, 0, 0, 0)

__device__ __forceinline__ unsigned short f2bf(float f) {
  union { float f; unsigned int u; } v; v.f = f;
  unsigned int r = v.u + 0x7fffu + ((v.u >> 16) & 1u);
  return (unsigned short)(r >> 16);
}

// v_cvt_pk_bf16_f32: dst = {lo: bf16(a), hi: bf16(b)} (T12 recipe, no builtin)
__device__ __forceinline__ int cvtpk(float a, float b) {
  int r;
  asm("v_cvt_pk_bf16_f32 %0, %1, %2" : "=v"(r) : "v"(a), "v"(b));
  return r;
}
// v_permlane32_swap_b32: a.hi-lanes <-> b.lo-lanes.
__device__ __forceinline__ void pswap(int& a, int& b) {
  asm("v_permlane32_swap_b32 %0, %1" : "+v"(a), "+v"(b));
}

// async 16B global -> LDS (wave-uniform LDS base + lane*16)
typedef __attribute__((address_space(1))) const unsigned int gu32;
typedef __attribute__((address_space(3))) unsigned int lu32;
__device__ __forceinline__ void async_cp16(const unsigned short* g, unsigned short* l) {
  __builtin_amdgcn_global_load_lds((gu32*)g, (lu32*)l, 16, 0, 0);
}

// ---------- fused: 4x W-transpose (z=0..3) + x fp32->bf16 (z=4) ----------
__global__ void prep_kernel(const float* __restrict__ x, unsigned short* __restrict__ xb,
                            const float* __restrict__ W0, const float* __restrict__ W1,
                            const float* __restrict__ W2, const float* __restrict__ W3,
                            unsigned short* __restrict__ T0, unsigned short* __restrict__ T1,
                            unsigned short* __restrict__ T2, unsigned short* __restrict__ T3) {
  const int z = blockIdx.z;
  if (z == 4) {  // x convert: 1024 blocks x 256 thr x 8 float4
    const int i0 = (blockIdx.y * 32 + blockIdx.x) * 2048 + threadIdx.x;
#pragma unroll
    for (int j = 0; j < 8; j++) {
      const int i = i0 + j * 256;
      const float4 v = reinterpret_cast<const float4*>(x)[i];
      ushort4 o;
      o.x = f2bf(v.x); o.y = f2bf(v.y); o.z = f2bf(v.z); o.w = f2bf(v.w);
      reinterpret_cast<ushort4*>(xb)[i] = o;
    }
    return;
  }
  __shared__ float tile[32][33];
  const float* W = (z == 0) ? W0 : (z == 1) ? W1 : (z == 2) ? W2 : W3;
  unsigned short* Wt = (z == 0) ? T0 : (z == 1) ? T1 : (z == 2) ? T2 : T3;
  int tx = threadIdx.x & 31, ty = threadIdx.x >> 5; // 32 x 8
  int bx = blockIdx.x, by = blockIdx.y;
#pragma unroll
  for (int i = 0; i < 4; i++) {
    int k = by * 32 + ty + i * 8;
    tile[ty + i * 8][tx] = W[k * Dsz + bx * 32 + tx];
  }
  __syncthreads();
#pragma unroll
  for (int i = 0; i < 4; i++) {
    int nrow = bx * 32 + ty + i * 8;
    Wt[nrow * Dsz + by * 32 + tx] = f2bf(tile[tx][ty + i * 8]);
  }
}

// ---------- 128x128-tile, BK=64, 512 threads (8 waves, 32x64 acc/wave) ----------
// XOR-swizzled async-staged bf16 GEMM, C = A[M,K] * Bt[N,K]^T.
// bm-chunked bijective XCD swizzle (verified r2: FETCH 103->41MB; r4 here:
// 76.8->49.2MB): XCD x owns bm in [8x,8x+8) x all bn -> per-XCD A = 2MB
// (L2-resident), B panel shared via L3.
enum { EPI_QKV = 0, EPI_OUT = 1 };

template <int EPI>
__global__ __launch_bounds__(512, 4)
void gemm_bk64(const unsigned short* __restrict__ A,
               const unsigned short* __restrict__ Bt,
               unsigned short* __restrict__ Qh,
               unsigned short* __restrict__ Kh,
               unsigned short* __restrict__ Vth,
               float* __restrict__ Out,
               const float* __restrict__ bias) {
  __shared__ unsigned short As[128 * 64];
  __shared__ unsigned short Bs[128 * 64];

  const int tid = threadIdx.x;
  const int w = tid >> 6, lane = tid & 63;
  const int l15 = lane & 15, quad = lane >> 4;
  const int wr = w >> 1, wc = w & 1;
  const int orig = blockIdx.y * gridDim.x + blockIdx.x;
  const int xcd = orig & 7, idx = orig >> 3;
  const int bm = (xcd << 3) | (idx & 7);
  const int bn = idx >> 3;
  const int rr = lane >> 3;                 // row within 8-row group
  const int scoff = ((lane & 7) ^ rr) * 8;  // swizzled source col (shorts)

  f32x4 acc[2][4];
#pragma unroll
  for (int i = 0; i < 2; i++)
#pragma unroll
    for (int j = 0; j < 4; j++) acc[i][j] = (f32x4){0.f, 0.f, 0.f, 0.f};

  const int rowA0 = bm * 128, rowB0 = bn * 128;

  for (int kt = 0; kt < Dsz / 64; kt++) {
#pragma unroll
    for (int i = 0; i < 2; i++) {
      const int r8 = w * 16 + i * 8;
      async_cp16(&A[(size_t)(rowA0 + r8 + rr) * Dsz + kt * 64 + scoff], &As[r8 * 64]);
      async_cp16(&Bt[(size_t)(rowB0 + r8 + rr) * Dsz + kt * 64 + scoff], &Bs[r8 * 64]);
    }
    __syncthreads();

#pragma unroll
    for (int ks = 0; ks < 2; ks++) {
      bf16x8 af[2], bfr[4];
#pragma unroll
      for (int t = 0; t < 2; t++) {
        const int ra = wr * 32 + t * 16 + l15;
        af[t] = *reinterpret_cast<const bf16x8*>(
            &As[ra * 64 + (((ks * 4 + quad) ^ (ra & 7)) * 8)]);
      }
#pragma unroll
      for (int t = 0; t < 4; t++) {
        const int rb = wc * 64 + t * 16 + l15;
        bfr[t] = *reinterpret_cast<const bf16x8*>(
            &Bs[rb * 64 + (((ks * 4 + quad) ^ (rb & 7)) * 8)]);
      }
#pragma unroll
      for (int i = 0; i < 2; i++)
#pragma unroll
        for (int j = 0; j < 4; j++)
          acc[i][j] = MFMA32(af[i], bfr[j], acc[i][j]);
    }
    __syncthreads();
  }

  if (EPI == EPI_QKV) {
    const int proj = (bn * 128) >> 10;  // block-uniform: 0=Q 1=K 2=V
#pragma unroll
    for (int i = 0; i < 2; i++) {
#pragma unroll
      for (int j = 0; j < 4; j++) {
        const int n = bn * 128 + wc * 64 + j * 16 + l15;
        const int nn = n & 1023, h = nn >> 6, hd = nn & 63;
        const int m0 = bm * 128 + wr * 32 + i * 16 + quad * 4;
        const int b = m0 >> 11, s0 = m0 & (Ssz - 1);
        if (proj == 0) {
#pragma unroll
          for (int r = 0; r < 4; r++)
            Qh[((size_t)(b * Hn + h) * Ssz + s0 + r) * HDsz + hd] =
                f2bf(acc[i][j][r] * (0.125f * LOG2E));
        } else if (proj == 1) {
#pragma unroll
          for (int r = 0; r < 4; r++)
            Kh[((size_t)(b * Hn + h) * Ssz + s0 + r) * HDsz + hd] = f2bf(acc[i][j][r]);
        } else {
          ushort4 o;
          o.x = f2bf(acc[i][j][0]); o.y = f2bf(acc[i][j][1]);
          o.z = f2bf(acc[i][j][2]); o.w = f2bf(acc[i][j][3]);
          *reinterpret_cast<ushort4*>(
              &Vth[((size_t)(b * Hn + h) * HDsz + hd) * Ssz + s0]) = o;
        }
      }
    }
  } else {
#pragma unroll
    for (int i = 0; i < 2; i++) {
#pragma unroll
      for (int j = 0; j < 4; j++) {
        const int n = bn * 128 + wc * 64 + j * 16 + l15;
        const int m0 = bm * 128 + wr * 32 + i * 16 + quad * 4;
#pragma unroll
        for (int r = 0; r < 4; r++)
          Out[(size_t)(m0 + r) * Dsz + n] = acc[i][j][r] + bias[n];
      }
    }
  }
}

// ---------- flash attention v8: 32x32 MFMA + KVBLK=128 (half the barrier drains) ----------
// v7 math kept byte-for-byte (swapped QK^T, in-reg softmax, cvt_pk+permlane32,
// PV on 32x32x16). ROUND-8 CHANGE: stage 128 kv per barrier pair — K as
// [128][64] (16KB, storage bit3 = i&1), V as two 64-col tiles Vs[2] (8KB each,
// byte-identical layout to v7) — then run the per-32-kv compute 4x (2 halves x
// 2 kt) between ONE __syncthreads pair. Drain events per CU: 68 -> 34; per-CU
// work stays exactly balanced (t-set {15-a,8+a,7-a,a} -> sum(t+1) = 34).
// Single-buffer retained (r3: dbuf's concurrent DMA-writes vs ds-reads cost
// 6.5e6 conflict cycles). T5 setprio wrapped around MFMA clusters (m191 +4-7%).
__global__ __launch_bounds__(256, 4)
void flash_kernel(const unsigned short* __restrict__ Q,
                  const unsigned short* __restrict__ Kg,
                  const unsigned short* __restrict__ Vt,
                  unsigned short* __restrict__ AO) {
  __shared__ unsigned short Ks[128 * 64];
  __shared__ unsigned short Vs[2][64 * 64];

  const int tid = threadIdx.x;
  const int w = tid >> 6, lane = tid & 63;
  const int l31 = lane & 31, hi = lane >> 5;
  const int rr = lane >> 3;

  const int linear = blockIdx.y * 16 + blockIdx.x;
  const int bh = (linear & 7) * 8 + ((linear >> 3) & 7);
  const int g = linear >> 6, gk = g >> 2, ga = g & 3;
  const int t = (gk == 0) ? 15 - ga : (gk == 1) ? 8 + ga : (gk == 2) ? 7 - ga : ga;

  const unsigned short* Qb = Q + (size_t)bh * Ssz * HDsz;
  const unsigned short* Kb = Kg + (size_t)bh * Ssz * HDsz;
  const unsigned short* Vb = Vt + (size_t)bh * HDsz * Ssz;
  const int b = bh / Hn, h = bh % Hn;

  // read-side swizzle nibble: row&7 = l31&7, (row>>3)&1 = (l31>>3)&1 for all
  // row = {half*64 + kt*32 + l31, ho*32 + l31} (offsets are multiples of 32)
  const int hl = (l31 & 7) ^ (((l31 >> 3) & 1) << 2);

  const int rowStart = t * 128 + w * 32;
  const int q = rowStart + l31;  // this lane's q-row (both halves share it)

  // Q as QK^T B-operand: col=q=lane&31, k = d = ks*16 + hi*8 + j
  bf16x8 qf[4];
#pragma unroll
  for (int ks = 0; ks < 4; ks++)
    qf[ks] = *reinterpret_cast<const bf16x8*>(
        &Qb[(size_t)q * HDsz + ks * 16 + hi * 8]);

  f32x16 oacc[2];
#pragma unroll
  for (int ho = 0; ho < 2; ho++)
#pragma unroll
    for (int r = 0; r < 16; r++) oacc[ho][r] = 0.f;
  float lpart = 0.f;

  const int nkb = t + 1;  // 128-kv tiles
  for (int kb = 0; kb < nkb; kb++) {
    const int kv0 = kb * 128;
    // stage K rows kv0..kv0+127 into Ks[128][64]; storage bit3 of row = i&1
#pragma unroll
    for (int i = 0; i < 4; i++) {
      const int r8 = w * 32 + i * 8;
      const int sc = ((lane & 7) ^ rr ^ ((i & 1) << 2)) * 8;
      async_cp16(&Kb[(size_t)(kv0 + r8 + rr) * HDsz + sc], &Ks[r8 * 64]);
    }
    // stage V cols kv0+c*64..+63 into Vs[c][64][64] (v7-identical layout)
#pragma unroll
    for (int c = 0; c < 2; c++)
#pragma unroll
      for (int i = 0; i < 2; i++) {
        const int r8 = w * 16 + i * 8;
        const int sc = ((lane & 7) ^ rr ^ (i << 2)) * 8;
        async_cp16(&Vb[(size_t)(r8 + rr) * Ssz + kv0 + c * 64 + sc], &Vs[c][r8 * 64]);
      }
    __syncthreads();

#pragma unroll
    for (int half = 0; half < 2; half++) {
      const int kvh = kv0 + half * 64;
#pragma unroll
      for (int kt = 0; kt < 2; kt++) {
        const bool skip = (kvh + kt * 32 >= rowStart + 32);  // wave-uniform
        if (skip) continue;

        // S^T tile [kv 32][q 32]: A = K (row=kv, k=d), B = Q
        f32x16 st;
#pragma unroll
        for (int r = 0; r < 16; r++) st[r] = 0.f;
        __builtin_amdgcn_s_setprio(1);
#pragma unroll
        for (int ks = 0; ks < 4; ks++) {
          const int row = half * 64 + kt * 32 + l31;
          bf16x8 kf = *reinterpret_cast<const bf16x8*>(
              &Ks[row * 64 + (((ks * 2 + hi) ^ hl) * 8)]);
          st = MFMA3232(kf, qf[ks], st);
        }
        __builtin_amdgcn_s_setprio(0);

        const bool needMask = (kvh + kt * 32 + 31 > rowStart);  // wave-uniform
        if (needMask) {
#pragma unroll
          for (int r = 0; r < 16; r++) {
            const int kv = kvh + kt * 32 + (r & 3) + 8 * (r >> 2) + 4 * hi;
            if (kv > q) st[r] = -1e30f;
          }
        }

        // p = exp2(s) (Q pre-scaled by log2e/8); lpart pairwise
        float e[16];
#pragma unroll
        for (int r = 0; r < 16; r++) e[r] = __builtin_amdgcn_exp2f(st[r]);
#pragma unroll
        for (int r = 0; r < 16; r += 4)
          lpart += (e[r] + e[r + 1]) + (e[r + 2] + e[r + 3]);

        // PV: per 16-kv step s, build A-frag via cvt_pk + permlane32_swap
#pragma unroll
        for (int s = 0; s < 2; s++) {
          int a0 = cvtpk(e[8 * s + 0], e[8 * s + 1]);
          int a1 = cvtpk(e[8 * s + 2], e[8 * s + 3]);
          int b0 = cvtpk(e[8 * s + 4], e[8 * s + 5]);
          int b1 = cvtpk(e[8 * s + 6], e[8 * s + 7]);
          pswap(a0, b0);  // -> words 0, 2
          pswap(a1, b1);  // -> words 1, 3
          union { int u[4]; bf16x8 v; } pa;
          pa.u[0] = a0; pa.u[1] = a1; pa.u[2] = b0; pa.u[3] = b1;
          const int t16 = kt * 2 + s;
          __builtin_amdgcn_s_setprio(1);
#pragma unroll
          for (int ho = 0; ho < 2; ho++) {
            const int row = ho * 32 + l31;
            bf16x8 vf = *reinterpret_cast<const bf16x8*>(
                &Vs[half][row * 64 + (((t16 * 2 + hi) ^ hl) * 8)]);
            oacc[ho] = MFMA3232(pa.v, vf, oacc[ho]);
          }
          __builtin_amdgcn_s_setprio(0);
        }
      }
    }
    __syncthreads();
  }

  // normalize: lf(q=l31) full row sum; redistribute to reg-rows via bpermute
  float lf = lpart + __shfl_xor(lpart, 32);
  float linv[16];
#pragma unroll
  for (int r = 0; r < 16; r++) {
    const int qloc = (r & 3) + 8 * (r >> 2) + 4 * hi;
    union { float f; int i; } cv;
    cv.f = lf;
    cv.i = __builtin_amdgcn_ds_bpermute(qloc * 4, cv.i);
    linv[r] = 1.f / cv.f;
  }
#pragma unroll
  for (int r = 0; r < 16; r++) {
    const int qloc = (r & 3) + 8 * (r >> 2) + 4 * hi;
    const size_t m = (size_t)b * Ssz + rowStart + qloc;
#pragma unroll
    for (int ho = 0; ho < 2; ho++) {
      const int n = h * HDsz + ho * 32 + l31;
      AO[m * Dsz + n] = f2bf(oacc[ho][r] * linv[r]);
    }
  }
}

extern "C" void kernel_launch(void* const* d_in, const int* in_sizes, int n_in,
                              void* d_out, int out_size, void* d_ws, size_t ws_size,
                              hipStream_t stream) {
  const float* x  = (const float*)d_in[0];
  const float* Wq = (const float*)d_in[1];
  const float* Wk = (const float*)d_in[2];
  const float* Wv = (const float*)d_in[3];
  const float* Wo = (const float*)d_in[4];
  const float* bo = (const float*)d_in[5];
  float* out = (float*)d_out;

  unsigned short* xb  = (unsigned short*)d_ws;
  unsigned short* Wqt = xb + (size_t)Msz * Dsz;   // Wqt/Wkt/Wvt consecutive = concat [3072][1024]
  unsigned short* Wkt = Wqt + (size_t)Dsz * Dsz;
  unsigned short* Wvt = Wkt + (size_t)Dsz * Dsz;
  unsigned short* Wot = Wvt + (size_t)Dsz * Dsz;
  unsigned short* Qh  = Wot + (size_t)Dsz * Dsz;
  unsigned short* Kh  = Qh + (size_t)Msz * Dsz;
  unsigned short* Vth = Kh + (size_t)Msz * Dsz;
  unsigned short* AO  = Vth + (size_t)Msz * Dsz;

  prep_kernel<<<dim3(32, 32, 5), 256, 0, stream>>>(
      x, xb, Wq, Wk, Wv, Wo, Wqt, Wkt, Wvt, Wot);

  // fused QKV projection: N = 3072 (proven 128x128 structure + XCD swizzle)
  gemm_bk64<EPI_QKV><<<dim3(3 * Dsz / 128, Msz / 128), 512, 0, stream>>>(
      xb, Wqt, Qh, Kh, Vth, nullptr, nullptr);

  flash_kernel<<<dim3(16, Bsz * Hn), 256, 0, stream>>>(Qh, Kh, Vth, AO);

  gemm_bk64<EPI_OUT><<<dim3(Dsz / 128, Msz / 128), 512, 0, stream>>>(
      AO, Wot, nullptr, nullptr, nullptr, out, bo);
}